// Round 1
// baseline (169.016 us; speedup 1.0000x reference)
//
#include <hip/hip_runtime.h>
#include <hip/hip_bf16.h>
#include <cstdint>

typedef __attribute__((ext_vector_type(8))) short short8;
typedef __attribute__((ext_vector_type(16))) float f32x16;

#if __has_builtin(__builtin_amdgcn_exp2f)
#define EXP2F(x) __builtin_amdgcn_exp2f(x)
#else
#define EXP2F(x) exp2f(x)
#endif

#define MFMA32(A, B, C) __builtin_amdgcn_mfma_f32_32x32x16_bf16((A), (B), (C), 0, 0, 0)

// fp32 -> bf16, round-to-nearest-even (values are finite; no NaN handling needed)
__device__ __forceinline__ unsigned short f2bf(float f) {
  unsigned int u = __builtin_bit_cast(unsigned int, f);
  u += 0x7FFFu + ((u >> 16) & 1u);
  return (unsigned short)(u >> 16);
}

// ---------------------------------------------------------------------------
// Projection: Y = X[16384x512] * W[512x64] + b, output bf16.
//   which=0: Q (folds softmax scale 1/8 * log2(e) so attention uses exp2)
//   which=1: K (natural [row][64] layout)
//   which=2: V stored transposed Vt[b][64][2048] (for PV A-operand loads)
// Wave = 32 rows, WG = 4 waves = 128 rows. A-frags straight from global fp32.
// W^T staged in LDS in two K-halves (stride 264 elems: 16B-aligned, 2-way
// bank aliasing only = free).
// ---------------------------------------------------------------------------
__global__ __launch_bounds__(256) void proj_kernel(
    const float* __restrict__ qin, const float* __restrict__ kin, const float* __restrict__ vin,
    const float* __restrict__ Wq, const float* __restrict__ bq,
    const float* __restrict__ Wk, const float* __restrict__ bk,
    const float* __restrict__ Wv, const float* __restrict__ bv,
    unsigned short* __restrict__ Qo, unsigned short* __restrict__ Ko,
    unsigned short* __restrict__ Vto)
{
  __shared__ unsigned short smem[64 * 264];   // 33.8 KB (reused as V-transpose buffer)
  const int which = blockIdx.y;
  const float* X    = (which == 0) ? qin : (which == 1) ? kin : vin;
  const float* W    = (which == 0) ? Wq  : (which == 1) ? Wk  : Wv;
  const float* bias = (which == 0) ? bq  : (which == 1) ? bk  : bv;

  const int lane = threadIdx.x & 63;
  const int wave = threadIdx.x >> 6;
  const int h = lane >> 5, l31 = lane & 31;
  const int rowbase = blockIdx.x * 128 + wave * 32;
  const float* xrow = X + (size_t)(rowbase + l31) * 512 + h * 8;

  f32x16 acc0 = {}; f32x16 acc1 = {};
  for (int half = 0; half < 2; ++half) {
    __syncthreads();
    for (int i = threadIdx.x; i < 256 * 64; i += 256) {
      int k = i >> 6, n = i & 63;
      smem[n * 264 + k] = f2bf(W[(half * 256 + k) * 64 + n]);
    }
    __syncthreads();
    const float* xh = xrow + half * 256;
    #pragma unroll 4
    for (int kc = 0; kc < 16; ++kc) {
      float4 a0 = *(const float4*)(xh + kc * 16);
      float4 a1 = *(const float4*)(xh + kc * 16 + 4);
      short8 af = { (short)f2bf(a0.x), (short)f2bf(a0.y), (short)f2bf(a0.z), (short)f2bf(a0.w),
                    (short)f2bf(a1.x), (short)f2bf(a1.y), (short)f2bf(a1.z), (short)f2bf(a1.w) };
      const unsigned short* wt = smem + kc * 16 + h * 8;
      short8 bf0 = *(const short8*)(wt + l31 * 264);
      short8 bf1 = *(const short8*)(wt + (l31 + 32) * 264);
      acc0 = MFMA32(af, bf0, acc0);
      acc1 = MFMA32(af, bf1, acc1);
    }
  }

  const float scale = (which == 0) ? 0.18033688f : 1.0f;  // (1/sqrt(64))*log2(e)
  const float bias0 = bias[l31], bias1 = bias[l31 + 32];

  if (which < 2) {
    unsigned short* Y = (which == 0) ? Qo : Ko;
    #pragma unroll
    for (int r = 0; r < 16; ++r) {
      int row = (r & 3) + 8 * (r >> 2) + 4 * h;   // C/D layout [m101]
      size_t base = (size_t)(rowbase + row) * 64;
      Y[base + l31]      = f2bf((acc0[r] + bias0) * scale);
      Y[base + l31 + 32] = f2bf((acc1[r] + bias1) * scale);
    }
  } else {
    __syncthreads();                 // everyone done reading W^T
    unsigned short* TB = smem;       // [64 n][136] transpose buffer
    #pragma unroll
    for (int r = 0; r < 16; ++r) {
      int row = (r & 3) + 8 * (r >> 2) + 4 * h;
      int sl = wave * 32 + row;
      TB[l31 * 136 + sl]        = f2bf(acc0[r] + bias0);
      TB[(l31 + 32) * 136 + sl] = f2bf(acc1[r] + bias1);
    }
    __syncthreads();
    int bidx = blockIdx.x >> 4;        // 16 blocks per batch (128 rows each)
    int s0 = (blockIdx.x & 15) * 128;
    for (int i = threadIdx.x; i < 64 * 128; i += 256) {
      int n = i >> 7, sl = i & 127;
      Vto[((size_t)bidx * 64 + n) * 2048 + s0 + sl] = TB[n * 136 + sl];
    }
  }
}

// ---------------------------------------------------------------------------
// Flash attention, transposed formulation:
//   S^T = K * Q^T  (A=K rows=keys, B=Q^T cols=q)  -> C: col=q(lane&31), row=key
//   O^T = Vt * P^T (A=Vt rows=vdim, B=P^T cols=q) -> C: col=q, row=vdim
// Key-wise softmax reduction is in-lane (16 regs) + one shfl_xor(32).
// P^T C->B relayout is a half-wave swap (shfl_xor 32) -- no LDS in main loop.
// WG = 512 thr = 8 waves; wave w handles q-tile (64 q) x keys [256w,256w+256).
// 8 partials tree-combined via 18 KB LDS. Grid (32 qtiles, 8 batches).
// ---------------------------------------------------------------------------
__global__ __launch_bounds__(512, 2) void attn_kernel(
    const unsigned short* __restrict__ Q, const unsigned short* __restrict__ K,
    const unsigned short* __restrict__ Vt, float* __restrict__ out)
{
  __shared__ float ObS[4][16][64];   // 16 KB O-merge staging
  __shared__ float MpS[4][64];
  __shared__ float LpS[4][64];

  const int tid = threadIdx.x;
  const int lane = tid & 63, w = tid >> 6;
  const int h = lane >> 5, l31 = lane & 31;
  const int b = blockIdx.y;
  const int q0 = blockIdx.x * 64;

  // resident Q B-frags: lane holds Q[q0+qt*32+l31][c*16 + h*8 .. +7]
  short8 qf[2][4];
  #pragma unroll
  for (int qt = 0; qt < 2; ++qt) {
    const unsigned short* qp = Q + ((size_t)(b * 2048 + q0 + qt * 32 + l31)) * 64 + h * 8;
    #pragma unroll
    for (int c = 0; c < 4; ++c) qf[qt][c] = *(const short8*)(qp + c * 16);
  }

  f32x16 o00 = {}, o01 = {}, o10 = {}, o11 = {};   // o[vt][qt], O^T accum
  float m0 = -1e30f, m1 = -1e30f, ls0 = 0.f, ls1 = 0.f;

  for (int st = 0; st < 8; ++st) {
    const int kb = w * 256 + st * 32;
    // K A-frags: lane holds K[kb+l31][c*16 + h*8 ..]
    short8 kf[4];
    const unsigned short* kp = K + ((size_t)(b * 2048 + kb + l31)) * 64 + h * 8;
    #pragma unroll
    for (int c = 0; c < 4; ++c) kf[c] = *(const short8*)(kp + c * 16);
    // Vt A-frags: lane holds Vt[vt*32+l31][kb + ck*16 + h*8 ..]
    short8 vf0[2], vf1[2];
    {
      const unsigned short* vp0 = Vt + ((size_t)(b * 64 + l31)) * 2048 + kb + h * 8;
      const unsigned short* vp1 = Vt + ((size_t)(b * 64 + 32 + l31)) * 2048 + kb + h * 8;
      vf0[0] = *(const short8*)(vp0);  vf0[1] = *(const short8*)(vp0 + 16);
      vf1[0] = *(const short8*)(vp1);  vf1[1] = *(const short8*)(vp1 + 16);
    }
    #pragma unroll
    for (int qt = 0; qt < 2; ++qt) {
      f32x16 sT = {};
      #pragma unroll
      for (int c = 0; c < 4; ++c) sT = MFMA32(kf[c], qf[qt][c], sT);
      // online softmax over keys (rows of sT): in-lane 16 + half-swap
      float mx = sT[0];
      #pragma unroll
      for (int r = 1; r < 16; ++r) mx = fmaxf(mx, sT[r]);
      mx = fmaxf(mx, __shfl_xor(mx, 32, 64));
      float mold = qt ? m1 : m0;
      float mnew = fmaxf(mold, mx);
      float alpha = EXP2F(mold - mnew);
      float rs = 0.f;
      float p[16];
      #pragma unroll
      for (int r = 0; r < 16; ++r) { p[r] = EXP2F(sT[r] - mnew); rs += p[r]; }
      rs += __shfl_xor(rs, 32, 64);
      // pack P to bf16 pairs; reg r holds key (r&3)+8*(r>>2)+4h
      unsigned int pk[8];
      #pragma unroll
      for (int i = 0; i < 8; ++i)
        pk[i] = (unsigned int)f2bf(p[2 * i]) | ((unsigned int)f2bf(p[2 * i + 1]) << 16);
      unsigned int ex[8];
      #pragma unroll
      for (int i = 0; i < 8; ++i) ex[i] = (unsigned int)__shfl_xor((int)pk[i], 32, 64);
      // B-operand frags for P^T: lane needs keys h*8..h*8+7 (+16 for chunk 1)
      uint4 cc0, cc1;
      if (h == 0) { cc0 = make_uint4(pk[0], pk[1], ex[0], ex[1]); cc1 = make_uint4(pk[4], pk[5], ex[4], ex[5]); }
      else        { cc0 = make_uint4(ex[2], ex[3], pk[2], pk[3]); cc1 = make_uint4(ex[6], ex[7], pk[6], pk[7]); }
      short8 P0 = __builtin_bit_cast(short8, cc0);
      short8 P1 = __builtin_bit_cast(short8, cc1);
      if (qt == 0) {
        m0 = mnew; ls0 = ls0 * alpha + rs;
        o00 *= alpha; o10 *= alpha;
        o00 = MFMA32(vf0[0], P0, o00); o00 = MFMA32(vf0[1], P1, o00);
        o10 = MFMA32(vf1[0], P0, o10); o10 = MFMA32(vf1[1], P1, o10);
      } else {
        m1 = mnew; ls1 = ls1 * alpha + rs;
        o01 *= alpha; o11 *= alpha;
        o01 = MFMA32(vf0[0], P0, o01); o01 = MFMA32(vf0[1], P1, o01);
        o11 = MFMA32(vf1[0], P0, o11); o11 = MFMA32(vf1[1], P1, o11);
      }
    }
  }

  // tree-combine the 8 key-split partials: 8 -> 4 -> 2 -> 1
  for (int half = 4; half > 0; half >>= 1) {
    const bool writer = (w >= half) && (w < 2 * half);
    const bool merger = (w < half);
    __syncthreads();
    if (writer && h == 0) {
      MpS[w - half][l31] = m0;      LpS[w - half][l31] = ls0;
      MpS[w - half][32 + l31] = m1; LpS[w - half][32 + l31] = ls1;
    }
    __syncthreads();
    float fb0 = 0.f, fb1 = 0.f;
    if (merger) {
      float pm0 = MpS[w][l31],      pl0 = LpS[w][l31];
      float pm1 = MpS[w][32 + l31], pl1 = LpS[w][32 + l31];
      float nm0 = fmaxf(m0, pm0), nm1 = fmaxf(m1, pm1);
      float fa0 = EXP2F(m0 - nm0); fb0 = EXP2F(pm0 - nm0);
      float fa1 = EXP2F(m1 - nm1); fb1 = EXP2F(pm1 - nm1);
      m0 = nm0; m1 = nm1;
      ls0 = ls0 * fa0 + pl0 * fb0; ls1 = ls1 * fa1 + pl1 * fb1;
      o00 *= fa0; o10 *= fa0; o01 *= fa1; o11 *= fa1;
    }
    __syncthreads();
    if (writer) { 
      #pragma unroll
      for (int r = 0; r < 16; ++r) ObS[w - half][r][lane] = o00[r]; }
    __syncthreads();
    if (merger) { 
      #pragma unroll
      for (int r = 0; r < 16; ++r) o00[r] += ObS[w][r][lane] * fb0; }
    __syncthreads();
    if (writer) { 
      #pragma unroll
      for (int r = 0; r < 16; ++r) ObS[w - half][r][lane] = o01[r]; }
    __syncthreads();
    if (merger) { 
      #pragma unroll
      for (int r = 0; r < 16; ++r) o01[r] += ObS[w][r][lane] * fb1; }
    __syncthreads();
    if (writer) { 
      #pragma unroll
      for (int r = 0; r < 16; ++r) ObS[w - half][r][lane] = o10[r]; }
    __syncthreads();
    if (merger) { 
      #pragma unroll
      for (int r = 0; r < 16; ++r) o10[r] += ObS[w][r][lane] * fb0; }
    __syncthreads();
    if (writer) { 
      #pragma unroll
      for (int r = 0; r < 16; ++r) ObS[w - half][r][lane] = o11[r]; }
    __syncthreads();
    if (merger) { 
      #pragma unroll
      for (int r = 0; r < 16; ++r) o11[r] += ObS[w][r][lane] * fb1; }
  }

  if (w == 0) {
    float i0 = 1.0f / ls0, i1 = 1.0f / ls1;
    o00 *= i0; o10 *= i0; o01 *= i1; o11 *= i1;
    // store O (transpose back): reg group g of frag (vt,qt) -> vdim vt*32+8g+4h+0..3
    #pragma unroll
    for (int qt = 0; qt < 2; ++qt) {
      int q = qt * 32 + l31;
      float* ob = out + ((size_t)(b * 2048 + q0 + q)) * 64 + 4 * h;
      const f32x16 a = qt ? o01 : o00;
      const f32x16 c = qt ? o11 : o10;
      #pragma unroll
      for (int g = 0; g < 4; ++g) {
        *(float4*)(ob + 8 * g)      = make_float4(a[4*g], a[4*g+1], a[4*g+2], a[4*g+3]);
        *(float4*)(ob + 32 + 8 * g) = make_float4(c[4*g], c[4*g+1], c[4*g+2], c[4*g+3]);
      }
    }
  }
}

extern "C" void kernel_launch(void* const* d_in, const int* in_sizes, int n_in,
                              void* d_out, int out_size, void* d_ws, size_t ws_size,
                              hipStream_t stream) {
  const float* qin = (const float*)d_in[0];
  const float* kin = (const float*)d_in[1];
  const float* vin = (const float*)d_in[2];
  const float* Wq  = (const float*)d_in[3];
  const float* bq  = (const float*)d_in[4];
  const float* Wk  = (const float*)d_in[5];
  const float* bk  = (const float*)d_in[6];
  const float* Wv  = (const float*)d_in[7];
  const float* bv  = (const float*)d_in[8];

  unsigned short* Qo  = (unsigned short*)d_ws;            // [8*2048][64] bf16 (pre-scaled)
  unsigned short* Ko  = Qo + (size_t)16384 * 64;          // [8*2048][64] bf16
  unsigned short* Vto = Ko + (size_t)16384 * 64;          // [8][64][2048] bf16 (transposed)
  float* out = (float*)d_out;

  hipLaunchKernelGGL(proj_kernel, dim3(128, 3), dim3(256), 0, stream,
                     qin, kin, vin, Wq, bq, Wk, bk, Wv, bv, Qo, Ko, Vto);
  hipLaunchKernelGGL(attn_kernel, dim3(32, 8), dim3(512), 0, stream, Qo, Ko, Vto, out);
}